// Round 14
// baseline (260.236 us; speedup 1.0000x reference)
//
#include <hip/hip_runtime.h>

typedef unsigned short u16;
typedef unsigned long long u64;
typedef short bf16x8 __attribute__((ext_vector_type(8)));
typedef float f32x4  __attribute__((ext_vector_type(4)));

#define NA 22       /* agents per graph */
#define FIN 32      /* input feature dim */
#define XS_STR 520  /* xs LDS row stride (u16): 1040B, conflict-free A-frag reads */
#define HS_STR 24   /* hs_t (transposed h) row stride (u16): [col][agent 0..23] */
#define AL_STR 24   /* alpha row stride (u16): [dst i][src j 0..23], 22,23 zeroed */

/* g_ws layout (u16): main B-frags then fused-attention (Wav) frags */
#define W1_OFF 0          /* 32 frags   */
#define W2_OFF 16384      /* 512 frags  */
#define W3_OFF 278528     /* 128 frags  */
#define E1_OFF 344064     /* 1 frag     */
#define E2_OFF 344576     /* 16 frags   */
#define E3_OFF 352768     /* 16 frags   */
#define WS_TOTAL 360960

/* Static device-side workspace: avoids d_ws entirely (its size was never
   guaranteed; OOB d_ws writes are the prime suspect for rounds 11-13's
   nondeterministic corruption). 705 KB, module-owned, rewritten per launch. */
__device__ u16 g_ws[WS_TOTAL];

__device__ float b2f(u16 u) {
    return __uint_as_float(((unsigned int)u) << 16);
}

__device__ u16 f2b(float f) {
    unsigned int x = __float_as_uint(f);
    x = (x + 0x7fffu + ((x >> 16) & 1u)) >> 16;  /* round-nearest-even */
    return (u16)x;
}

/* W [K][N] fp32 -> bf16 B-frag layout, scatter form (coalesced reads):
   element (k,n) -> frag(kt=k/32, nt=n/16), lane=(k%32/8)*16 + n%16, j=k%8 */
__global__ void swizzle_kernel(const float* W1, const float* W2, const float* W3)
{
    int t = blockIdx.x * 256 + threadIdx.x;
    const float* W; int NT, nshift, base, loc;
    if (t < W2_OFF)      { W = W1; NT = 32; nshift = 9; base = W1_OFF; loc = t; }
    else if (t < W3_OFF) { W = W2; NT = 32; nshift = 9; base = W2_OFF; loc = t - W2_OFF; }
    else if (t < E1_OFF) { W = W3; NT = 8;  nshift = 7; base = W3_OFF; loc = t - W3_OFF; }
    else { return; }
    int k = loc >> nshift;
    int n = loc & ((1 << nshift) - 1);
    u16 v = f2b(W[loc]);
    int kt = k >> 5, quad = (k & 31) >> 3, j = k & 7;
    int nt = n >> 4, lm = n & 15;
    int lane = (quad << 4) | lm;
    g_ws[base + (((kt * NT + nt) << 9) | (lane << 3) | j)] = v;
}

/* Wav[f][col] = sum_c W[f][h*128+c]*av[h][c]: fused s/d columns, frag layout.
   cols 0..H-1 = src heads, H..2H-1 = dst heads, rest zero. */
__global__ void wav_kernel(const float* W1, const float* as1, const float* ad1,
                           const float* W2, const float* as2, const float* ad2,
                           const float* W3, const float* as3, const float* ad3)
{
    int t = blockIdx.x * 256 + threadIdx.x;   /* 16896 total */
    const float* W; const float* asp; const float* adp;
    int H, N, base, loc;
    if (t < 512)        { W = W1; asp = as1; adp = ad1; H = 4; N = 512; base = E1_OFF; loc = t; }
    else if (t < 8704)  { W = W2; asp = as2; adp = ad2; H = 4; N = 512; base = E2_OFF; loc = t - 512; }
    else if (t < 16896) { W = W3; asp = as3; adp = ad3; H = 1; N = 128; base = E3_OFF; loc = t - 8704; }
    else { return; }
    int kt = loc >> 9, r = loc & 511;
    int lane = r >> 3, j = r & 7;
    int quad = lane >> 4, lm = lane & 15;
    u16 outv = 0;
    if (lm < 2 * H) {
        int h = (H == 4) ? (lm & 3) : 0;
        int which = (H == 4) ? (lm >> 2) : lm;
        const float* av = which ? adp : asp;
        int k = kt * 32 + quad * 8 + j;
        float s = 0.f;
        for (int c = 0; c < 128; ++c) { s += W[k * N + h * 128 + c] * av[h * 128 + c]; }
        outv = f2b(s);
    }
    g_ws[base + (kt << 9) + (lane << 3) + j] = outv;
}

__device__ __forceinline__ u64 pack4(f32x4 v) {
    return (u64)f2b(v[0]) | ((u64)f2b(v[1]) << 16)
         | ((u64)f2b(v[2]) << 32) | ((u64)f2b(v[3]) << 48);
}

template<int KT, int NT, int NTW, int H>
__device__ __forceinline__ void gat_layer(
    const u16* Wsw, const u16* Wext, const float* bias,
    u16* xs, u16* hs_t, float* sv, float* dv, u16* al)
{
    int tid  = threadIdx.x;
    int wave = tid >> 6, lane = tid & 63;
    int quad = lane >> 4, lm = lane & 15;

    /* ---------- GEMM h = x@W (+ fused s/d columns on wave 0) ---------- */
    {
        int r1 = 16 + lm; if (r1 >= NA) { r1 = lm; }   /* dummy valid row */
        const u16* a0base = xs + lm * XS_STR + quad * 8;
        const u16* a1base = xs + r1 * XS_STR + quad * 8;
        const u16* wbase  = Wsw + ((wave * NTW) << 9) + (lane << 3);
        const u16* ebase  = Wext + (lane << 3);

        f32x4 acc0[NTW], acc1[NTW], accE0, accE1;
        f32x4 z4 = {0.f, 0.f, 0.f, 0.f};
        #pragma unroll
        for (int n = 0; n < NTW; ++n) { acc0[n] = z4; acc1[n] = z4; }
        accE0 = z4; accE1 = z4;

        bf16x8 bbuf[2][NTW], ebuf[2], ab0[2], ab1[2];
        #pragma unroll
        for (int n = 0; n < NTW; ++n) { bbuf[0][n] = *(const bf16x8*)(wbase + (n << 9)); }
        if (wave == 0) { ebuf[0] = *(const bf16x8*)(ebase); }
        ab0[0] = *(const bf16x8*)(a0base);
        ab1[0] = *(const bf16x8*)(a1base);

        #pragma unroll
        for (int kt = 0; kt < KT; ++kt) {
            const int cur = kt & 1;
            const int nxt = cur ^ 1;
            if (kt + 1 < KT) {
                const u16* wn = wbase + (((kt + 1) * NT) << 9);
                #pragma unroll
                for (int n = 0; n < NTW; ++n) { bbuf[nxt][n] = *(const bf16x8*)(wn + (n << 9)); }
                if (wave == 0) { ebuf[nxt] = *(const bf16x8*)(ebase + ((kt + 1) << 9)); }
                ab0[nxt] = *(const bf16x8*)(a0base + (kt + 1) * 32);
                ab1[nxt] = *(const bf16x8*)(a1base + (kt + 1) * 32);
            }
            #pragma unroll
            for (int n = 0; n < NTW; ++n) {
                acc0[n] = __builtin_amdgcn_mfma_f32_16x16x32_bf16(ab0[cur], bbuf[cur][n], acc0[n], 0, 0, 0);
                acc1[n] = __builtin_amdgcn_mfma_f32_16x16x32_bf16(ab1[cur], bbuf[cur][n], acc1[n], 0, 0, 0);
            }
            if (wave == 0) {
                accE0 = __builtin_amdgcn_mfma_f32_16x16x32_bf16(ab0[cur], ebuf[cur], accE0, 0, 0, 0);
                accE1 = __builtin_amdgcn_mfma_f32_16x16x32_bf16(ab1[cur], ebuf[cur], accE1, 0, 0, 0);
            }
        }

        /* epilogue: h -> hs_t[col][agent] as packed b64 stores */
        #pragma unroll
        for (int n = 0; n < NTW; ++n) {
            u16* colp = hs_t + ((wave * NTW + n) * 16 + lm) * HS_STR;
            *(u64*)(colp + quad * 4) = pack4(acc0[n]);
            if (quad < 2) {                          /* agents 16..23 (22,23 pad) */
                *(u64*)(colp + 16 + quad * 4) = pack4(acc1[n]);
            }
        }
        /* fused attention coefficients (fp32, exact) */
        if (wave == 0) {
            #pragma unroll
            for (int r = 0; r < 4; ++r) {
                int row0 = quad * 4 + r;
                if (lm < H)            { sv[lm * NA + row0] = accE0[r]; }
                else if (lm < 2 * H)   { dv[(lm - H) * NA + row0] = accE0[r]; }
                int row1 = 16 + quad * 4 + r;
                if (row1 < NA) {
                    if (lm < H)          { sv[lm * NA + row1] = accE1[r]; }
                    else if (lm < 2 * H) { dv[(lm - H) * NA + row1] = accE1[r]; }
                }
            }
        }
    }
    __syncthreads();

    /* ---------- softmax -> alpha (bf16, A-frag row layout) ---------- */
    if (tid < H * NA) {
        int hh = tid / NA;
        int ii = tid - hh * NA;
        float di = dv[tid];
        float lg[NA];
        float mx = -1.0e30f, ss = 0.0f;
        #pragma unroll
        for (int j = 0; j < NA; ++j) {
            float l = di + sv[hh * NA + j];
            l = fmaxf(l, 0.2f * l);                  /* leaky relu 0.2 */
            lg[j] = l;
            mx = fmaxf(mx, l);
        }
        #pragma unroll
        for (int j = 0; j < NA; ++j) {
            float e = __expf(lg[j] - mx);
            lg[j] = e;
            ss += e;
        }
        float inv = 1.0f / ss;
        u16* arow = al + (hh * NA + ii) * AL_STR;
        #pragma unroll
        for (int j = 0; j < NA; ++j) { arow[j] = f2b(lg[j] * inv); }
        arow[22] = 0; arow[23] = 0;                  /* zero K-pad */
    }
    __syncthreads();

    /* ---------- aggregate out = alpha @ h via MFMA; +bias, relu -> xs ---------- */
    {
        int head = (H == 4) ? wave : 0;
        const u16* albase = al + head * NA * AL_STR;
        bf16x8 zb = {0, 0, 0, 0, 0, 0, 0, 0};
        f32x4 z4 = {0.f, 0.f, 0.f, 0.f};
        int r1 = 16 + lm; if (r1 >= NA) { r1 = lm; }
        bf16x8 pa0 = (quad < 3) ? *(const bf16x8*)(albase + lm * AL_STR + quad * 8) : zb;
        bf16x8 pa1 = (quad < 3) ? *(const bf16x8*)(albase + r1 * AL_STR + quad * 8) : zb;

        f32x4 agg0[NTW], agg1[NTW];
        float bv[NTW];
        #pragma unroll
        for (int n = 0; n < NTW; ++n) {
            int col = (wave * NTW + n) * 16 + lm;
            bv[n] = bias[col];
            bf16x8 pb = *(const bf16x8*)(hs_t + col * HS_STR + quad * 8);
            agg0[n] = __builtin_amdgcn_mfma_f32_16x16x32_bf16(pa0, pb, z4, 0, 0, 0);
            agg1[n] = __builtin_amdgcn_mfma_f32_16x16x32_bf16(pa1, pb, z4, 0, 0, 0);
        }
        #pragma unroll
        for (int n = 0; n < NTW; ++n) {
            int col = (wave * NTW + n) * 16 + lm;
            #pragma unroll
            for (int r = 0; r < 4; ++r) {
                int row0 = quad * 4 + r;
                xs[row0 * XS_STR + col] = f2b(fmaxf(agg0[n][r] + bv[n], 0.0f));
                int row1 = 16 + quad * 4 + r;
                if (row1 < NA) {
                    xs[row1 * XS_STR + col] = f2b(fmaxf(agg1[n][r] + bv[n], 0.0f));
                }
            }
        }
    }
    __syncthreads();
}

__global__ void __launch_bounds__(256, 2)
pressgnn_kernel(const float* feats,
                const float* b1, const float* b2, const float* b3,
                const float* Wc, const float* bc,
                float* out)
{
    __shared__ __align__(16) u16 xs[NA * XS_STR];        /* 22880 B */
    __shared__ __align__(16) u16 hs_t[512 * HS_STR + 8]; /* 24592 B */
    __shared__ __align__(16) u16 al[4 * NA * AL_STR];    /*  4224 B */
    __shared__ float sv[4 * NA];
    __shared__ float dv[4 * NA];
    __shared__ float pool[128];

    int g = blockIdx.x;
    int tid = threadIdx.x;

    /* load this graph's features: [NA][FIN] fp32 -> bf16 LDS */
    for (int i = tid; i < NA * FIN; i += 256) {
        int row = i >> 5;
        int col = i & 31;
        xs[row * XS_STR + col] = f2b(feats[g * NA * FIN + i]);
    }
    __syncthreads();

    gat_layer<1,  32, 8, 4>(g_ws + W1_OFF, g_ws + E1_OFF, b1, xs, hs_t, sv, dv, al);
    gat_layer<16, 32, 8, 4>(g_ws + W2_OFF, g_ws + E2_OFF, b2, xs, hs_t, sv, dv, al);
    gat_layer<16, 8,  2, 1>(g_ws + W3_OFF, g_ws + E3_OFF, b3, xs, hs_t, sv, dv, al);
    /* xs now holds [NA][128] relu'd (H=1: head-mean is identity) */

    /* global mean pool over agents + final linear 128->1 */
    if (tid < 128) {
        float s = 0.0f;
        #pragma unroll
        for (int a = 0; a < NA; ++a) { s += b2f(xs[a * XS_STR + tid]); }
        pool[tid] = (s / 22.0f) * Wc[tid];
    }
    __syncthreads();
    if (tid == 0) {
        float t = 0.0f;
        for (int c = 0; c < 128; ++c) { t += pool[c]; }
        out[g] = t + bc[0];
    }
}

extern "C" void kernel_launch(void* const* d_in, const int* in_sizes, int n_in,
                              void* d_out, int out_size, void* d_ws, size_t ws_size,
                              hipStream_t stream) {
    const float* feats = (const float*)d_in[0];
    const float* W1  = (const float*)d_in[1];
    const float* as1 = (const float*)d_in[2];
    const float* ad1 = (const float*)d_in[3];
    const float* b1  = (const float*)d_in[4];
    const float* W2  = (const float*)d_in[5];
    const float* as2 = (const float*)d_in[6];
    const float* ad2 = (const float*)d_in[7];
    const float* b2  = (const float*)d_in[8];
    const float* W3  = (const float*)d_in[9];
    const float* as3 = (const float*)d_in[10];
    const float* ad3 = (const float*)d_in[11];
    const float* b3  = (const float*)d_in[12];
    const float* Wc  = (const float*)d_in[13];
    const float* bc  = (const float*)d_in[14];
    float* out = (float*)d_out;
    (void)d_ws; (void)ws_size;   /* d_ws deliberately unused: size not guaranteed */

    /* per-launch weight prep into the module-owned device workspace */
    swizzle_kernel<<<dim3(1344), dim3(256), 0, stream>>>(W1, W2, W3);
    wav_kernel<<<dim3(66), dim3(256), 0, stream>>>(W1, as1, ad1, W2, as2, ad2,
                                                   W3, as3, ad3);

    /* one block per graph; graph count == output element count (B*T = 4096) */
    pressgnn_kernel<<<dim3(out_size), dim3(256), 0, stream>>>(
        feats, b1, b2, b3, Wc, bc, out);
}